// Round 14
// baseline (142.130 us; speedup 1.0000x reference)
//
#include <hip/hip_runtime.h>
#include <cstdint>

// Head attention: x[4,4096,1024] fp32, Wq/Wk/Wv[1024,64] fp32 -> out[4,4096,64] fp32.
// Round 23 (on r21 best, 132.7): K1 W path moved from DMA+LDS to direct
// L2->register prefetch. wt2 (384 KB) is L2-resident; LDS staging of it was
// pure overhead (3 DMA/thread + 24KB LDS-write + 6 ds_read/wave per step).
// Now: wfA/wfB named reg sets (static indexing), loaded one step ahead as
// 6 coalesced bf16x8 global loads/wave; vmcnt(8) top wait covers x-DMA(s)
// LDS visibility + W(s) regs. K1 LDS 80->32 KB. x path identical to r19/r21.
//  K0: wt_prep  - W -> bf16 per-64k-step LDS-image slabs; Wq pre-scaled (frozen)
//  K1: qkv_proj - 64-row blocks, 512 thr, x-DMA dbuf + W reg-prefetch from L2
//  K2: flash    - fat tile (b, qt2-128rows, h4), paired KV slabs, in-reg P (r21)
//  K3: combine  - out = sum_h O_h / sum_h l_h over bf16 partials (frozen)

typedef __bf16 bf16;
typedef __bf16 bf16x4 __attribute__((ext_vector_type(4)));
typedef __bf16 bf16x8 __attribute__((ext_vector_type(8)));
typedef float  f32x4  __attribute__((ext_vector_type(4)));

#define MFMA16(a, b, c) __builtin_amdgcn_mfma_f32_16x16x32_bf16((a), (b), (c), 0, 0, 0)

#if __has_builtin(__builtin_amdgcn_exp2f)
#define EXP2(x) __builtin_amdgcn_exp2f(x)
#else
#define EXP2(x) exp2f(x)
#endif

#define B_SZ 4
#define T_SZ 4096
#define C_SZ 1024
#define H_SZ 64
#define M_SZ (B_SZ * T_SZ)
#define QSCALE (1.4426950408889634f / 32.0f)   // log2(e)/sqrt(1024)
#define P_O 8192                               // bf16 elems per O-partial (128x64)
#define P_L 128                                // f32 elems per l-partial

// async 16B global->LDS DMA; LDS dest is wave-uniform base + lane*16.
__device__ __forceinline__ void dma16(const void* g, void* l) {
    __builtin_amdgcn_global_load_lds(
        (const __attribute__((address_space(1))) uint32_t*)(uintptr_t)g,
        (__attribute__((address_space(3))) uint32_t*)(uint32_t)(uintptr_t)l,
        16, 0, 0);
}

// top-of-iter: counted wait (leave N newest loads in flight) + join barrier.
#define WAIT_BARRIER(N) do {                                       \
    asm volatile("s_waitcnt vmcnt(" #N ")" ::: "memory");          \
    __builtin_amdgcn_s_barrier();                                  \
    __builtin_amdgcn_sched_barrier(0);                             \
} while (0)

// bottom-of-iter: raw barrier (NO vmcnt drain -- prefetch stays in flight).
#define BOT_BARRIER() do {                                         \
    __builtin_amdgcn_sched_barrier(0);                             \
    __builtin_amdgcn_s_barrier();                                  \
    __builtin_amdgcn_sched_barrier(0);                             \
} while (0)

// -------------------------------------------------------------------------
// K0: wt2 image, per 64-k outer step s: elem off =
//   s*12288 + sub*6144 + quad*1536 + n*8 + j  (k = s*64+sub*32+quad*8+j, n = 0..191).
// -------------------------------------------------------------------------
__global__ __launch_bounds__(256) void wt_prep(
    const float* __restrict__ Wq, const float* __restrict__ Wk,
    const float* __restrict__ Wv, bf16* __restrict__ wt2)
{
    const int n4 = blockIdx.x, t = threadIdx.x;
    const int nbase = n4 * 4;
    const float* W = (nbase < 64) ? Wq : (nbase < 128 ? Wk : Wv);
    const float sc = (nbase < 64) ? QSCALE : 1.0f;
    const int ncol = nbase & 63;
    #pragma unroll
    for (int i = 0; i < 4; ++i) {
        const int k = i * 256 + t;
        const float4 v = *(const float4*)(W + (size_t)k * H_SZ + ncol);
        const float vals[4] = {v.x, v.y, v.z, v.w};
        const size_t base = (size_t)(k >> 6) * 12288 + (size_t)((k >> 5) & 1) * 6144
                          + (size_t)((k >> 3) & 3) * 1536 + (k & 7);
        #pragma unroll
        for (int m = 0; m < 4; ++m)
            wt2[base + (size_t)(nbase + m) * 8] = (bf16)(vals[m] * sc);
    }
}

// -------------------------------------------------------------------------
// K1: qkv. grid 256 x 512 (8 waves: rh = wave>>2 row-half, cg = wave&3 col
// group). Block = 64 rows x 192 fused cols, 16 steps of BK=64, slab phase
// staggered by block. LDS: xs 2x16KB only (32 KB).
// Per step s: issue x-DMA(s+1) [2] + W reg-loads(s+1) [6, L2-hot, into the
// OTHER named wf set]; WAIT vmcnt(8) (x(s) LDS-visible, W(s) regs done);
// barrier; compute s; raw barrier. Tail waits vmcnt(0). Loop unrolled x2 so
// wfA/wfB indexing is static (no scratch).
// x slab image per step (r19): [row64][16 chunks], dest chunk d = r*16 +
// (c ^ (r&7)); DMA dest linear (d = tid, tid+512), per-lane SRC remapped ->
// each wave-instr reads 4 rows x 256B contiguous. Frag reads apply same XOR.
// -------------------------------------------------------------------------
__global__ __launch_bounds__(512) void qkv_proj(
    const float* __restrict__ x, const bf16* __restrict__ wt2,
    bf16* __restrict__ qw, bf16* __restrict__ kw2, bf16* __restrict__ vtw2)
{
    const int m0 = blockIdx.x * 64;
    const int tid = threadIdx.x;
    const int wave = tid >> 6, lane = tid & 63;
    const int quad = lane >> 4, l15 = lane & 15;
    const int rh = wave >> 2;                      // row-half 0/1
    const int cg = wave & 3;                       // col group 0..3
    const int phase = blockIdx.x & 15;             // slab-phase stagger

    __shared__ __align__(16) float xs[2][64 * 64];        // 2 x 16 KB

    f32x4 acc[2][3] = {};                          // [mg][ntile]

    // x DMA: thread covers dest chunks d = tid (rows 0..31) and tid+512
    // (rows 32..63). r0 = tid>>4, cc = tid&15, src chunk c = cc ^ (r0&7)
    // ((r0+32)&7 == r0&7). Src byte (per step se): (m0+r)*4096 + se*256 + c*16.
    const int r0 = tid >> 4;
    const int csrc = (tid & 15) ^ (r0 & 7);
    const char* xg0 = (const char*)x + (size_t)(m0 + r0) * 4096 + (size_t)csrc * 16;
    const char* xg1 = xg0 + (size_t)32 * 4096;
    // W reg-prefetch base: wf(se, ss, i) at wt2 + se*12288 + ss*6144
    //   + quad*1536 + (cg*3+i)*128 + l15*8   (16B contiguous per lane).
    const bf16* wbase = wt2 + (size_t)quad * 1536 + (size_t)(cg * 3) * 128
                      + (size_t)l15 * 8;

    auto stage_x = [&](int s, int buf) {
        const size_t se = (size_t)((s + phase) & 15);
        char* xl = (char*)(&xs[buf][0]) + (size_t)tid * 16;
        dma16(xg0 + se * 256, xl);
        dma16(xg1 + se * 256, xl + 8192);
    };
    auto load_w = [&](int s, bf16x8 (&wf)[2][3]) {
        const size_t se = (size_t)((s + phase) & 15);
        const bf16* p = wbase + se * 12288;
        #pragma unroll
        for (int ss = 0; ss < 2; ++ss)
            #pragma unroll
            for (int i = 0; i < 3; ++i)
                wf[ss][i] = *(const bf16x8*)(p + ss * 6144 + i * 128);
    };
    auto compute = [&](int s, const bf16x8 (&wf)[2][3]) {
        const float* xb = &xs[s & 1][0];
        #pragma unroll
        for (int ss = 0; ss < 2; ++ss) {
            bf16x8 a[2];
            const int cbase = ss * 8 + quad * 2;   // lo chunk; hi = cbase+1
            #pragma unroll
            for (int mg = 0; mg < 2; ++mg) {
                const int row = rh * 32 + mg * 16 + l15;
                const int rx = row & 7;
                const float* xrow = xb + row * 64;
                const f32x4 lo = *(const f32x4*)(xrow + ((cbase ^ rx) << 2));
                const f32x4 hi = *(const f32x4*)(xrow + (((cbase + 1) ^ rx) << 2));
                a[mg][0] = (bf16)lo[0]; a[mg][1] = (bf16)lo[1];
                a[mg][2] = (bf16)lo[2]; a[mg][3] = (bf16)lo[3];
                a[mg][4] = (bf16)hi[0]; a[mg][5] = (bf16)hi[1];
                a[mg][6] = (bf16)hi[2]; a[mg][7] = (bf16)hi[3];
            }
            #pragma unroll
            for (int i = 0; i < 3; ++i)
                #pragma unroll
                for (int mg = 0; mg < 2; ++mg)
                    acc[mg][i] = MFMA16(a[mg], wf[ss][i], acc[mg][i]);
        }
    };

    bf16x8 wfA[2][3], wfB[2][3];

    // prologue: x(0) DMA + W(0) reg-loads (8 in flight)
    stage_x(0, 0);
    load_w(0, wfA);

    #define K1_STEP(S, CUR, NXT) do {                                  \
        if ((S) < 15) {                                                \
            stage_x((S) + 1, ((S) + 1) & 1);                           \
            load_w((S) + 1, NXT);                                      \
            WAIT_BARRIER(8);                                           \
        } else {                                                       \
            WAIT_BARRIER(0);                                           \
        }                                                              \
        compute((S), CUR);                                             \
        BOT_BARRIER();                                                 \
    } while (0)

    for (int s2 = 0; s2 < 16; s2 += 2) {
        K1_STEP(s2,     wfA, wfB);
        K1_STEP(s2 + 1, wfB, wfA);
    }
    #undef K1_STEP

    // epilogue: row t = m0+rh*32+mg*16+quad*4+r, col n = (cg*3+i)*16+l15
    #pragma unroll
    for (int mg = 0; mg < 2; ++mg)
        #pragma unroll
        for (int i = 0; i < 3; ++i) {
            const int n = (cg * 3 + i) * 16 + l15;
            const int which = n >> 6, col = n & 63;
            #pragma unroll
            for (int r = 0; r < 4; ++r) {
                const int t = m0 + rh * 32 + mg * 16 + quad * 4 + r;
                const bf16 v = (bf16)acc[mg][i][r];
                if (which == 0) {
                    qw[(size_t)t * H_SZ + col] = v;
                } else if (which == 1) {
                    // K slab: jt*4096 + ((col>>5)*4 + ((col>>3)&3))*512 + (t&63)*8 + (col&7)
                    kw2[(size_t)(t >> 6) * 4096
                        + (size_t)(((col >> 5) << 2) + ((col >> 3) & 3)) * 512
                        + (size_t)(t & 63) * 8 + (col & 7)] = v;
                } else {
                    // V slab, kv-permuted for in-register P:
                    // p = ((t6>>2)&3)*8 + (t6&3)*2 + ((t6>>4)&1) + (t6>>5)*32
                    const int t6 = t & 63;
                    const int p = ((t6 >> 2) & 3) * 8 + (t6 & 3) * 2
                                + ((t6 >> 4) & 1) + (t6 >> 5) * 32;
                    vtw2[(size_t)(t >> 6) * 4096
                         + (size_t)(p >> 3) * 512 + (size_t)col * 8 + (p & 7)] = v;
                }
            }
        }
}

// -------------------------------------------------------------------------
// K2: causal flash, fat tile, in-reg P, KVBLK=128 (r21 exact). grid 512 x 256.
// Item (b, qt2 in 0..31, h in 0..3): 128 q-rows, 4 waves x 32 rows.
// Tile list for h: jt = h + 4k. Two tiles per sync window: prefetch pair
// (8 DMAs) -> WAIT(8); tails WAIT(4)/WAIT(0). kvs[2][2][8192] = 64KB LDS.
// QK swapped (s4t = MFMA16(K,Q)); vtw2 kv-perm makes P fragments in-register.
// Partials: O bf16 (128x64) -> pbuf_o, l f32 (128) -> pbuf_l.
// -------------------------------------------------------------------------
__global__ __launch_bounds__(256) void flash_attn(
    const bf16* __restrict__ qw, const bf16* __restrict__ kw2,
    const bf16* __restrict__ vtw2, bf16* __restrict__ pbuf_o,
    float* __restrict__ pbuf_l)
{
    const int bx = blockIdx.x;
    const int item = (bx & 1) ? (511 - (bx >> 1)) : (bx >> 1);  // serpentine
    const int qt2 = 31 - (item >> 4);                           // heavy first
    const int b   = (item >> 2) & 3;
    const int h   = item & 3;
    const int i0  = qt2 * 128;
    const int nkv = qt2 * 2 + 2;     // kv tiles 0..2*qt2+1 cover the 128 q-rows
    const int n   = (nkv > h) ? ((nkv - 1 - h) >> 2) + 1 : 0;   // tiles for this h

    const int tid = threadIdx.x;
    const int wave = tid >> 6, lane = tid & 63;
    const int quad = lane >> 4, l15 = lane & 15;

    __shared__ __align__(16) bf16 kvs[2][2][8192];   // [buf][sub][K 8K | V 8K]

    // Q frags (B-operand role): rows i0 + wave*32 + mg2*16 + l15, head quad*8 (+32)
    bf16x8 aq[2][2];
    #pragma unroll
    for (int mg2 = 0; mg2 < 2; ++mg2) {
        const bf16* qp = qw + ((size_t)b * T_SZ + i0 + wave * 32 + mg2 * 16 + l15) * H_SZ
                       + quad * 8;
        aq[mg2][0] = *(const bf16x8*)qp;
        aq[mg2][1] = *(const bf16x8*)(qp + 32);
    }
    const bf16 onev = (bf16)1.0f;
    const bf16x8 vone = {onev, onev, onev, onev, onev, onev, onev, onev};

    const char* kgb = (const char*)kw2 + (size_t)b * 524288;
    const char* vgb = (const char*)vtw2 + (size_t)b * 524288;

    f32x4 o[2][4] = {};
    f32x4 osum[2] = {};

    auto stage = [&](int k, int buf, int sub) {
        const int jt = h + 4 * k;
        const char* ks = kgb + (size_t)jt * 8192;
        const char* vs = vgb + (size_t)jt * 8192;
        char* dst = (char*)(&kvs[buf][sub][0]) + (size_t)tid * 16;
        dma16(ks + (size_t)tid * 16, dst);
        dma16(ks + 4096 + (size_t)tid * 16, dst + 4096);
        dma16(vs + (size_t)tid * 16, dst + 8192);
        dma16(vs + 4096 + (size_t)tid * 16, dst + 12288);
    };

    auto compute = [&](int k, int buf, int sub) {
        const int jt = h + 4 * k;
        const bf16* kb = &kvs[buf][sub][0];
        const bf16* vb = kb + 4096;

        // QK swapped: A = K-frag (rows = kv), B = Q-frag (cols = q).
        f32x4 s4t[4][2] = {};                      // [ct][mg2]
        __builtin_amdgcn_s_setprio(1);
        #pragma unroll
        for (int ct = 0; ct < 4; ++ct) {
            const bf16x8 k0 = *(const bf16x8*)(kb + (0 * 4 + quad) * 512 + (ct * 16 + l15) * 8);
            const bf16x8 k1 = *(const bf16x8*)(kb + (1 * 4 + quad) * 512 + (ct * 16 + l15) * 8);
            #pragma unroll
            for (int mg2 = 0; mg2 < 2; ++mg2) {
                s4t[ct][mg2] = MFMA16(k0, aq[mg2][0], s4t[ct][mg2]);
                s4t[ct][mg2] = MFMA16(k1, aq[mg2][1], s4t[ct][mg2]);
            }
        }
        __builtin_amdgcn_s_setprio(0);

        // causal mask (swapped layout): q = i0+wave*32+mg2*16+l15,
        // kv = jt*64 + ct*16 + quad*4 + rr; only top two kv tiles cross.
        if (jt >= 2 * qt2) {
            #pragma unroll
            for (int mg2 = 0; mg2 < 2; ++mg2) {
                const int gq = i0 + wave * 32 + mg2 * 16 + l15;
                #pragma unroll
                for (int ct = 0; ct < 4; ++ct) {
                    const int gkv0 = jt * 64 + ct * 16 + quad * 4;
                    #pragma unroll
                    for (int rr = 0; rr < 4; ++rr)
                        if (gkv0 + rr > gq) s4t[ct][mg2][rr] = -3.0e38f;
                }
            }
        }

        // P fragments entirely in-register (kv-perm matches vtw2):
        // pa[mg2][frag][j] = exp2(s4t[(j&1)+2*frag][mg2][j>>1])
        bf16x8 pa[2][2];
        #pragma unroll
        for (int mg2 = 0; mg2 < 2; ++mg2)
            #pragma unroll
            for (int j = 0; j < 8; ++j) {
                pa[mg2][0][j] = (bf16)EXP2(s4t[j & 1][mg2][j >> 1]);
                pa[mg2][1][j] = (bf16)EXP2(s4t[2 + (j & 1)][mg2][j >> 1]);
            }

        // PV: each V frag read once, used for both row-groups.
        __builtin_amdgcn_s_setprio(1);
        #pragma unroll
        for (int ht = 0; ht < 4; ++ht) {
            const bf16x8 v0 = *(const bf16x8*)(vb + (0 * 4 + quad) * 512 + (ht * 16 + l15) * 8);
            const bf16x8 v1 = *(const bf16x8*)(vb + (1 * 4 + quad) * 512 + (ht * 16 + l15) * 8);
            #pragma unroll
            for (int mg2 = 0; mg2 < 2; ++mg2) {
                o[mg2][ht] = MFMA16(pa[mg2][0], v0, o[mg2][ht]);
                o[mg2][ht] = MFMA16(pa[mg2][1], v1, o[mg2][ht]);
            }
        }
        #pragma unroll
        for (int mg2 = 0; mg2 < 2; ++mg2) {
            osum[mg2] = MFMA16(pa[mg2][0], vone, osum[mg2]);
            osum[mg2] = MFMA16(pa[mg2][1], vone, osum[mg2]);
        }
        __builtin_amdgcn_s_setprio(0);
    };

    if (n > 0) stage(0, 0, 0);
    if (n > 1) stage(1, 0, 1);

    int c = 0;
    for (int i = 0; i < n; i += 2, c ^= 1) {
        if (i + 3 < n) {
            stage(i + 2, c ^ 1, 0); stage(i + 3, c ^ 1, 1);
            WAIT_BARRIER(8);                       // previous pair complete
        } else if (i + 2 < n) {
            stage(i + 2, c ^ 1, 0);
            WAIT_BARRIER(4);                       // previous pair complete
        } else {
            WAIT_BARRIER(0);                       // tail: drain
        }
        compute(i, c, 0);
        if (i + 1 < n) compute(i + 1, c, 1);
        BOT_BARRIER();   // reads of kvs[c] done before it is re-staged
    }

    // epilogue: partial O rows L = wave*32 + mg2*16 + quad*4 + rr (O as bf16)
    bf16* pb_o = pbuf_o + (size_t)(((b * 32 + qt2) * 4) + h) * P_O;
    float* pb_l = pbuf_l + (size_t)(((b * 32 + qt2) * 4) + h) * P_L;
    #pragma unroll
    for (int mg2 = 0; mg2 < 2; ++mg2) {
        const int L0 = wave * 32 + mg2 * 16 + quad * 4;
        #pragma unroll
        for (int ht = 0; ht < 4; ++ht)
            #pragma unroll
            for (int rr = 0; rr < 4; ++rr)
                pb_o[(L0 + rr) * 64 + ht * 16 + l15] = (bf16)o[mg2][ht][rr];
        if (l15 == 0) {
            #pragma unroll
            for (int rr = 0; rr < 4; ++rr)
                pb_l[L0 + rr] = osum[mg2][rr];
        }
    }
}

// -------------------------------------------------------------------------
// K3: combine (frozen). grid 256 x 256. out = sum_h O_h / sum_h l_h.
// Block = 64 rows of one (b,qt2) 128-row partial set (half = bx&1).
// -------------------------------------------------------------------------
__global__ __launch_bounds__(256) void combine(
    const bf16* __restrict__ pbuf_o, const float* __restrict__ pbuf_l,
    float* __restrict__ out)
{
    const int bq2 = blockIdx.x >> 1, tid = threadIdx.x;
    const int row = ((blockIdx.x & 1) << 6) + (tid >> 2);   // 0..127
    const int c0 = (tid & 3) * 16;

    float a[16] = {};
    float l = 0.f;
    #pragma unroll
    for (int h = 0; h < 4; ++h) {
        const bf16* ph = pbuf_o + (size_t)(bq2 * 4 + h) * P_O + row * 64 + c0;
        const bf16x8 v0 = *(const bf16x8*)ph;
        const bf16x8 v1 = *(const bf16x8*)(ph + 8);
        #pragma unroll
        for (int j = 0; j < 8; ++j) {
            a[j]     += (float)v0[j];
            a[8 + j] += (float)v1[j];
        }
        l += pbuf_l[(size_t)(bq2 * 4 + h) * P_L + row];
    }
    const float inv = 1.0f / l;
    float* op = out + ((size_t)bq2 * 128 + row) * 64 + c0;
    #pragma unroll
    for (int g = 0; g < 4; ++g) {
        f32x4 v = {a[g * 4], a[g * 4 + 1], a[g * 4 + 2], a[g * 4 + 3]};
        *(f32x4*)(op + g * 4) = v * inv;
    }
}

extern "C" void kernel_launch(void* const* d_in, const int* in_sizes, int n_in,
                              void* d_out, int out_size, void* d_ws, size_t ws_size,
                              hipStream_t stream) {
    const float* x  = (const float*)d_in[0];
    const float* Wq = (const float*)d_in[1];
    const float* Wk = (const float*)d_in[2];
    const float* Wv = (const float*)d_in[3];

    bf16* qw   = (bf16*)d_ws;                          // 2 MB, plain [t][h]
    bf16* kw2  = qw + (size_t)M_SZ * H_SZ;             // 2 MB, per-kv-tile slabs
    bf16* vtw2 = kw2 + (size_t)M_SZ * H_SZ;            // 2 MB, kv-permuted slabs
    bf16* wt2  = vtw2 + (size_t)M_SZ * H_SZ;           // 384 KB, per-step slabs
    bf16* pbuf_o = wt2 + 3 * 64 * 1024;                // 8 MB bf16 O partials
    float* pbuf_l = (float*)(pbuf_o + (size_t)512 * P_O);  // 256 KB l partials
    float* out = (float*)d_out;

    wt_prep<<<48, 256, 0, stream>>>(Wq, Wk, Wv, wt2);
    qkv_proj<<<M_SZ / 64, 512, 0, stream>>>(x, wt2, qw, kw2, vtw2);
    flash_attn<<<512, 256, 0, stream>>>(qw, kw2, vtw2, pbuf_o, pbuf_l);
    combine<<<256, 256, 0, stream>>>(pbuf_o, pbuf_l, out);
}

// Round 15
// 132.190 us; speedup vs baseline: 1.0752x; 1.0752x over previous
//
#include <hip/hip_runtime.h>
#include <cstdint>

// Head attention: x[4,4096,1024] fp32, Wq/Wk/Wv[1024,64] fp32 -> out[4,4096,64] fp32.
// Round 24: r23 REVERTED (W reg-prefetch killed LDS broadcast amortization:
// +390MB L2 traffic, +9.4us). Base = r21 (132.7 best). NEW: K1 triple-buffered
// single-barrier rotation -- stage(s+2) issued AFTER compute(s) (its buffer's
// readers are past the top-of-s barrier), so the bottom barrier is deleted.
// 16 barriers instead of 32; LDS 120KB (still 1 block/CU); vmcnt(5) top wait
// completes stage(s) (2 compute phases of cover), tail vmcnt(0).
//  K0: wt_prep  - W -> bf16 per-64k-step LDS-image slabs; Wq pre-scaled (frozen)
//  K1: qkv_proj - 64-row blocks, 512 thr, BK=64, 3-buf 1-barrier rotation
//  K2: flash    - fat tile (b, qt2-128rows, h4), paired KV slabs, in-reg P (r21)
//  K3: combine  - out = sum_h O_h / sum_h l_h over bf16 partials (frozen)

typedef __bf16 bf16;
typedef __bf16 bf16x4 __attribute__((ext_vector_type(4)));
typedef __bf16 bf16x8 __attribute__((ext_vector_type(8)));
typedef float  f32x4  __attribute__((ext_vector_type(4)));

#define MFMA16(a, b, c) __builtin_amdgcn_mfma_f32_16x16x32_bf16((a), (b), (c), 0, 0, 0)

#if __has_builtin(__builtin_amdgcn_exp2f)
#define EXP2(x) __builtin_amdgcn_exp2f(x)
#else
#define EXP2(x) exp2f(x)
#endif

#define B_SZ 4
#define T_SZ 4096
#define C_SZ 1024
#define H_SZ 64
#define M_SZ (B_SZ * T_SZ)
#define QSCALE (1.4426950408889634f / 32.0f)   // log2(e)/sqrt(1024)
#define P_O 8192                               // bf16 elems per O-partial (128x64)
#define P_L 128                                // f32 elems per l-partial

// async 16B global->LDS DMA; LDS dest is wave-uniform base + lane*16.
__device__ __forceinline__ void dma16(const void* g, void* l) {
    __builtin_amdgcn_global_load_lds(
        (const __attribute__((address_space(1))) uint32_t*)(uintptr_t)g,
        (__attribute__((address_space(3))) uint32_t*)(uint32_t)(uintptr_t)l,
        16, 0, 0);
}

// top-of-iter: counted wait (leave N newest loads in flight) + join barrier.
#define WAIT_BARRIER(N) do {                                       \
    asm volatile("s_waitcnt vmcnt(" #N ")" ::: "memory");          \
    __builtin_amdgcn_s_barrier();                                  \
    __builtin_amdgcn_sched_barrier(0);                             \
} while (0)

// bottom-of-iter: raw barrier (NO vmcnt drain -- prefetch stays in flight).
#define BOT_BARRIER() do {                                         \
    __builtin_amdgcn_sched_barrier(0);                             \
    __builtin_amdgcn_s_barrier();                                  \
    __builtin_amdgcn_sched_barrier(0);                             \
} while (0)

// -------------------------------------------------------------------------
// K0: wt2 image, per 64-k outer step s: elem off =
//   s*12288 + sub*6144 + quad*1536 + n*8 + j  (k = s*64+sub*32+quad*8+j, n = 0..191).
// -------------------------------------------------------------------------
__global__ __launch_bounds__(256) void wt_prep(
    const float* __restrict__ Wq, const float* __restrict__ Wk,
    const float* __restrict__ Wv, bf16* __restrict__ wt2)
{
    const int n4 = blockIdx.x, t = threadIdx.x;
    const int nbase = n4 * 4;
    const float* W = (nbase < 64) ? Wq : (nbase < 128 ? Wk : Wv);
    const float sc = (nbase < 64) ? QSCALE : 1.0f;
    const int ncol = nbase & 63;
    #pragma unroll
    for (int i = 0; i < 4; ++i) {
        const int k = i * 256 + t;
        const float4 v = *(const float4*)(W + (size_t)k * H_SZ + ncol);
        const float vals[4] = {v.x, v.y, v.z, v.w};
        const size_t base = (size_t)(k >> 6) * 12288 + (size_t)((k >> 5) & 1) * 6144
                          + (size_t)((k >> 3) & 3) * 1536 + (k & 7);
        #pragma unroll
        for (int m = 0; m < 4; ++m)
            wt2[base + (size_t)(nbase + m) * 8] = (bf16)(vals[m] * sc);
    }
}

// -------------------------------------------------------------------------
// K1: qkv. grid 256 x 512 (8 waves: rh = wave>>2 row-half, cg = wave&3 col
// group). Block = 64 rows x 192 fused cols, 16 steps of BK=64, slab phase
// staggered by block. TRIPLE-buffered slabs (x 16KB + W 24KB per buffer,
// 120KB LDS), ONE barrier per step:
//   top of s: wait vmcnt(5) [completes stage(s); stage(s+1) stays in flight]
//             + barrier                                   (s=15: vmcnt(0))
//   compute s from buf s%3
//   stage(s+2) into buf (s+2)%3  [readers of that buffer passed the barrier]
// x slab image per step: [row64][16 chunks], dest chunk d = r*16+(c^(r&7));
// DMA dest linear (d = tid, tid+512), per-lane SRC remapped -> each
// wave-instr reads 4 rows x 256B contiguous. Frag reads apply same XOR.
// -------------------------------------------------------------------------
__global__ __launch_bounds__(512) void qkv_proj(
    const float* __restrict__ x, const bf16* __restrict__ wt2,
    bf16* __restrict__ qw, bf16* __restrict__ kw2, bf16* __restrict__ vtw2)
{
    const int m0 = blockIdx.x * 64;
    const int tid = threadIdx.x;
    const int wave = tid >> 6, lane = tid & 63;
    const int quad = lane >> 4, l15 = lane & 15;
    const int rh = wave >> 2;                      // row-half 0/1
    const int cg = wave & 3;                       // col group 0..3
    const int phase = blockIdx.x & 15;             // slab-phase stagger

    __shared__ __align__(16) float xs[3][64 * 64];        // 3 x 16 KB
    __shared__ __align__(16) bf16  ws[3][2 * 4 * 192 * 8];// 3 x 24 KB

    f32x4 acc[2][3] = {};                          // [mg][ntile]

    // x DMA: thread covers dest chunks d = tid (rows 0..31) and tid+512
    // (rows 32..63). r0 = tid>>4, cc = tid&15, src chunk c = cc ^ (r0&7)
    // ((r0+32)&7 == r0&7). Src byte (per step se): (m0+r)*4096 + se*256 + c*16.
    const int r0 = tid >> 4;
    const int csrc = (tid & 15) ^ (r0 & 7);
    const char* xg0 = (const char*)x + (size_t)(m0 + r0) * 4096 + (size_t)csrc * 16;
    const char* xg1 = xg0 + (size_t)32 * 4096;
    const char* wg = (const char*)wt2 + (size_t)tid * 16;

    auto stage = [&](int s, int buf) {
        const size_t se = (size_t)((s + phase) & 15);
        char* xl = (char*)(&xs[buf][0]) + (size_t)tid * 16;
        char* wl = (char*)(&ws[buf][0]) + (size_t)tid * 16;
        dma16(xg0 + se * 256, xl);
        dma16(xg1 + se * 256, xl + 8192);
        #pragma unroll
        for (int i = 0; i < 3; ++i)
            dma16(wg + se * 24576 + (size_t)i * 8192, wl + (size_t)i * 8192);
    };

    stage(0, 0);
    stage(1, 1);

    for (int s = 0; s < 16; ++s) {
        if (s == 15) {
            WAIT_BARRIER(0);                       // only stage(15) in flight
        } else {
            WAIT_BARRIER(5);                       // stage(s) complete
        }
        const int bufc = s % 3;
        const float* xb = &xs[bufc][0];
        const bf16*  wb = &ws[bufc][0];

        #pragma unroll
        for (int ss = 0; ss < 2; ++ss) {
            bf16x8 a[2];
            const int cbase = ss * 8 + quad * 2;   // lo chunk; hi = cbase+1
            #pragma unroll
            for (int mg = 0; mg < 2; ++mg) {
                const int row = rh * 32 + mg * 16 + l15;
                const int rx = row & 7;
                const float* xrow = xb + row * 64;
                const f32x4 lo = *(const f32x4*)(xrow + ((cbase ^ rx) << 2));
                const f32x4 hi = *(const f32x4*)(xrow + (((cbase + 1) ^ rx) << 2));
                a[mg][0] = (bf16)lo[0]; a[mg][1] = (bf16)lo[1];
                a[mg][2] = (bf16)lo[2]; a[mg][3] = (bf16)lo[3];
                a[mg][4] = (bf16)hi[0]; a[mg][5] = (bf16)hi[1];
                a[mg][6] = (bf16)hi[2]; a[mg][7] = (bf16)hi[3];
            }
            #pragma unroll
            for (int i = 0; i < 3; ++i) {
                const int nt = cg * 3 + i;
                const bf16x8 wf = *(const bf16x8*)(wb + ss * 6144 + quad * 1536
                                                   + (nt * 16 + l15) * 8);
                #pragma unroll
                for (int mg = 0; mg < 2; ++mg)
                    acc[mg][i] = MFMA16(a[mg], wf, acc[mg][i]);
            }
        }

        __builtin_amdgcn_sched_barrier(0);
        if (s + 2 < 16) stage(s + 2, (s + 2) % 3); // buffer freed by top barrier
        __builtin_amdgcn_sched_barrier(0);
    }

    // epilogue: row t = m0+rh*32+mg*16+quad*4+r, col n = (cg*3+i)*16+l15
    #pragma unroll
    for (int mg = 0; mg < 2; ++mg)
        #pragma unroll
        for (int i = 0; i < 3; ++i) {
            const int n = (cg * 3 + i) * 16 + l15;
            const int which = n >> 6, col = n & 63;
            #pragma unroll
            for (int r = 0; r < 4; ++r) {
                const int t = m0 + rh * 32 + mg * 16 + quad * 4 + r;
                const bf16 v = (bf16)acc[mg][i][r];
                if (which == 0) {
                    qw[(size_t)t * H_SZ + col] = v;
                } else if (which == 1) {
                    // K slab: jt*4096 + ((col>>5)*4 + ((col>>3)&3))*512 + (t&63)*8 + (col&7)
                    kw2[(size_t)(t >> 6) * 4096
                        + (size_t)(((col >> 5) << 2) + ((col >> 3) & 3)) * 512
                        + (size_t)(t & 63) * 8 + (col & 7)] = v;
                } else {
                    // V slab, kv-permuted for in-register P:
                    // p = ((t6>>2)&3)*8 + (t6&3)*2 + ((t6>>4)&1) + (t6>>5)*32
                    const int t6 = t & 63;
                    const int p = ((t6 >> 2) & 3) * 8 + (t6 & 3) * 2
                                + ((t6 >> 4) & 1) + (t6 >> 5) * 32;
                    vtw2[(size_t)(t >> 6) * 4096
                         + (size_t)(p >> 3) * 512 + (size_t)col * 8 + (p & 7)] = v;
                }
            }
        }
}

// -------------------------------------------------------------------------
// K2: causal flash, fat tile, in-reg P, KVBLK=128 (r21 exact). grid 512 x 256.
// Item (b, qt2 in 0..31, h in 0..3): 128 q-rows, 4 waves x 32 rows.
// Tile list for h: jt = h + 4k. Two tiles per sync window: prefetch pair
// (8 DMAs) -> WAIT(8); tails WAIT(4)/WAIT(0). kvs[2][2][8192] = 64KB LDS.
// QK swapped (s4t = MFMA16(K,Q)); vtw2 kv-perm makes P fragments in-register.
// Partials: O bf16 (128x64) -> pbuf_o, l f32 (128) -> pbuf_l.
// -------------------------------------------------------------------------
__global__ __launch_bounds__(256) void flash_attn(
    const bf16* __restrict__ qw, const bf16* __restrict__ kw2,
    const bf16* __restrict__ vtw2, bf16* __restrict__ pbuf_o,
    float* __restrict__ pbuf_l)
{
    const int bx = blockIdx.x;
    const int item = (bx & 1) ? (511 - (bx >> 1)) : (bx >> 1);  // serpentine
    const int qt2 = 31 - (item >> 4);                           // heavy first
    const int b   = (item >> 2) & 3;
    const int h   = item & 3;
    const int i0  = qt2 * 128;
    const int nkv = qt2 * 2 + 2;     // kv tiles 0..2*qt2+1 cover the 128 q-rows
    const int n   = (nkv > h) ? ((nkv - 1 - h) >> 2) + 1 : 0;   // tiles for this h

    const int tid = threadIdx.x;
    const int wave = tid >> 6, lane = tid & 63;
    const int quad = lane >> 4, l15 = lane & 15;

    __shared__ __align__(16) bf16 kvs[2][2][8192];   // [buf][sub][K 8K | V 8K]

    // Q frags (B-operand role): rows i0 + wave*32 + mg2*16 + l15, head quad*8 (+32)
    bf16x8 aq[2][2];
    #pragma unroll
    for (int mg2 = 0; mg2 < 2; ++mg2) {
        const bf16* qp = qw + ((size_t)b * T_SZ + i0 + wave * 32 + mg2 * 16 + l15) * H_SZ
                       + quad * 8;
        aq[mg2][0] = *(const bf16x8*)qp;
        aq[mg2][1] = *(const bf16x8*)(qp + 32);
    }
    const bf16 onev = (bf16)1.0f;
    const bf16x8 vone = {onev, onev, onev, onev, onev, onev, onev, onev};

    const char* kgb = (const char*)kw2 + (size_t)b * 524288;
    const char* vgb = (const char*)vtw2 + (size_t)b * 524288;

    f32x4 o[2][4] = {};
    f32x4 osum[2] = {};

    auto stage = [&](int k, int buf, int sub) {
        const int jt = h + 4 * k;
        const char* ks = kgb + (size_t)jt * 8192;
        const char* vs = vgb + (size_t)jt * 8192;
        char* dst = (char*)(&kvs[buf][sub][0]) + (size_t)tid * 16;
        dma16(ks + (size_t)tid * 16, dst);
        dma16(ks + 4096 + (size_t)tid * 16, dst + 4096);
        dma16(vs + (size_t)tid * 16, dst + 8192);
        dma16(vs + 4096 + (size_t)tid * 16, dst + 12288);
    };

    auto compute = [&](int k, int buf, int sub) {
        const int jt = h + 4 * k;
        const bf16* kb = &kvs[buf][sub][0];
        const bf16* vb = kb + 4096;

        // QK swapped: A = K-frag (rows = kv), B = Q-frag (cols = q).
        f32x4 s4t[4][2] = {};                      // [ct][mg2]
        __builtin_amdgcn_s_setprio(1);
        #pragma unroll
        for (int ct = 0; ct < 4; ++ct) {
            const bf16x8 k0 = *(const bf16x8*)(kb + (0 * 4 + quad) * 512 + (ct * 16 + l15) * 8);
            const bf16x8 k1 = *(const bf16x8*)(kb + (1 * 4 + quad) * 512 + (ct * 16 + l15) * 8);
            #pragma unroll
            for (int mg2 = 0; mg2 < 2; ++mg2) {
                s4t[ct][mg2] = MFMA16(k0, aq[mg2][0], s4t[ct][mg2]);
                s4t[ct][mg2] = MFMA16(k1, aq[mg2][1], s4t[ct][mg2]);
            }
        }
        __builtin_amdgcn_s_setprio(0);

        // causal mask (swapped layout): q = i0+wave*32+mg2*16+l15,
        // kv = jt*64 + ct*16 + quad*4 + rr; only top two kv tiles cross.
        if (jt >= 2 * qt2) {
            #pragma unroll
            for (int mg2 = 0; mg2 < 2; ++mg2) {
                const int gq = i0 + wave * 32 + mg2 * 16 + l15;
                #pragma unroll
                for (int ct = 0; ct < 4; ++ct) {
                    const int gkv0 = jt * 64 + ct * 16 + quad * 4;
                    #pragma unroll
                    for (int rr = 0; rr < 4; ++rr)
                        if (gkv0 + rr > gq) s4t[ct][mg2][rr] = -3.0e38f;
                }
            }
        }

        // P fragments entirely in-register (kv-perm matches vtw2):
        // pa[mg2][frag][j] = exp2(s4t[(j&1)+2*frag][mg2][j>>1])
        bf16x8 pa[2][2];
        #pragma unroll
        for (int mg2 = 0; mg2 < 2; ++mg2)
            #pragma unroll
            for (int j = 0; j < 8; ++j) {
                pa[mg2][0][j] = (bf16)EXP2(s4t[j & 1][mg2][j >> 1]);
                pa[mg2][1][j] = (bf16)EXP2(s4t[2 + (j & 1)][mg2][j >> 1]);
            }

        // PV: each V frag read once, used for both row-groups.
        __builtin_amdgcn_s_setprio(1);
        #pragma unroll
        for (int ht = 0; ht < 4; ++ht) {
            const bf16x8 v0 = *(const bf16x8*)(vb + (0 * 4 + quad) * 512 + (ht * 16 + l15) * 8);
            const bf16x8 v1 = *(const bf16x8*)(vb + (1 * 4 + quad) * 512 + (ht * 16 + l15) * 8);
            #pragma unroll
            for (int mg2 = 0; mg2 < 2; ++mg2) {
                o[mg2][ht] = MFMA16(pa[mg2][0], v0, o[mg2][ht]);
                o[mg2][ht] = MFMA16(pa[mg2][1], v1, o[mg2][ht]);
            }
        }
        #pragma unroll
        for (int mg2 = 0; mg2 < 2; ++mg2) {
            osum[mg2] = MFMA16(pa[mg2][0], vone, osum[mg2]);
            osum[mg2] = MFMA16(pa[mg2][1], vone, osum[mg2]);
        }
        __builtin_amdgcn_s_setprio(0);
    };

    if (n > 0) stage(0, 0, 0);
    if (n > 1) stage(1, 0, 1);

    int c = 0;
    for (int i = 0; i < n; i += 2, c ^= 1) {
        if (i + 3 < n) {
            stage(i + 2, c ^ 1, 0); stage(i + 3, c ^ 1, 1);
            WAIT_BARRIER(8);                       // previous pair complete
        } else if (i + 2 < n) {
            stage(i + 2, c ^ 1, 0);
            WAIT_BARRIER(4);                       // previous pair complete
        } else {
            WAIT_BARRIER(0);                       // tail: drain
        }
        compute(i, c, 0);
        if (i + 1 < n) compute(i + 1, c, 1);
        BOT_BARRIER();   // reads of kvs[c] done before it is re-staged
    }

    // epilogue: partial O rows L = wave*32 + mg2*16 + quad*4 + rr (O as bf16)
    bf16* pb_o = pbuf_o + (size_t)(((b * 32 + qt2) * 4) + h) * P_O;
    float* pb_l = pbuf_l + (size_t)(((b * 32 + qt2) * 4) + h) * P_L;
    #pragma unroll
    for (int mg2 = 0; mg2 < 2; ++mg2) {
        const int L0 = wave * 32 + mg2 * 16 + quad * 4;
        #pragma unroll
        for (int ht = 0; ht < 4; ++ht)
            #pragma unroll
            for (int rr = 0; rr < 4; ++rr)
                pb_o[(L0 + rr) * 64 + ht * 16 + l15] = (bf16)o[mg2][ht][rr];
        if (l15 == 0) {
            #pragma unroll
            for (int rr = 0; rr < 4; ++rr)
                pb_l[L0 + rr] = osum[mg2][rr];
        }
    }
}

// -------------------------------------------------------------------------
// K3: combine (frozen). grid 256 x 256. out = sum_h O_h / sum_h l_h.
// Block = 64 rows of one (b,qt2) 128-row partial set (half = bx&1).
// -------------------------------------------------------------------------
__global__ __launch_bounds__(256) void combine(
    const bf16* __restrict__ pbuf_o, const float* __restrict__ pbuf_l,
    float* __restrict__ out)
{
    const int bq2 = blockIdx.x >> 1, tid = threadIdx.x;
    const int row = ((blockIdx.x & 1) << 6) + (tid >> 2);   // 0..127
    const int c0 = (tid & 3) * 16;

    float a[16] = {};
    float l = 0.f;
    #pragma unroll
    for (int h = 0; h < 4; ++h) {
        const bf16* ph = pbuf_o + (size_t)(bq2 * 4 + h) * P_O + row * 64 + c0;
        const bf16x8 v0 = *(const bf16x8*)ph;
        const bf16x8 v1 = *(const bf16x8*)(ph + 8);
        #pragma unroll
        for (int j = 0; j < 8; ++j) {
            a[j]     += (float)v0[j];
            a[8 + j] += (float)v1[j];
        }
        l += pbuf_l[(size_t)(bq2 * 4 + h) * P_L + row];
    }
    const float inv = 1.0f / l;
    float* op = out + ((size_t)bq2 * 128 + row) * 64 + c0;
    #pragma unroll
    for (int g = 0; g < 4; ++g) {
        f32x4 v = {a[g * 4], a[g * 4 + 1], a[g * 4 + 2], a[g * 4 + 3]};
        *(f32x4*)(op + g * 4) = v * inv;
    }
}

extern "C" void kernel_launch(void* const* d_in, const int* in_sizes, int n_in,
                              void* d_out, int out_size, void* d_ws, size_t ws_size,
                              hipStream_t stream) {
    const float* x  = (const float*)d_in[0];
    const float* Wq = (const float*)d_in[1];
    const float* Wk = (const float*)d_in[2];
    const float* Wv = (const float*)d_in[3];

    bf16* qw   = (bf16*)d_ws;                          // 2 MB, plain [t][h]
    bf16* kw2  = qw + (size_t)M_SZ * H_SZ;             // 2 MB, per-kv-tile slabs
    bf16* vtw2 = kw2 + (size_t)M_SZ * H_SZ;            // 2 MB, kv-permuted slabs
    bf16* wt2  = vtw2 + (size_t)M_SZ * H_SZ;           // 384 KB, per-step slabs
    bf16* pbuf_o = wt2 + 3 * 64 * 1024;                // 8 MB bf16 O partials
    float* pbuf_l = (float*)(pbuf_o + (size_t)512 * P_O);  // 256 KB l partials
    float* out = (float*)d_out;

    wt_prep<<<48, 256, 0, stream>>>(Wq, Wk, Wv, wt2);
    qkv_proj<<<M_SZ / 64, 512, 0, stream>>>(x, wt2, qw, kw2, vtw2);
    flash_attn<<<512, 256, 0, stream>>>(qw, kw2, vtw2, pbuf_o, pbuf_l);
    combine<<<256, 256, 0, stream>>>(pbuf_o, pbuf_l, out);
}